// Round 1
// baseline (108.533 us; speedup 1.0000x reference)
//
#include <hip/hip_runtime.h>

// MelMeanFilteredMSE: out = mean( (M @ (10^(mo/10) - 10^(tg/10)))^2 )
// M is banded (variable-width mean filter, width <= 21, band monotone in i).
// Strategy: sliding-window running sum along frequency axis, one pass over
// inputs (268 MB -> memory-bound, floor ~43 us).

#define F 1025
#define TT 2048
#define BB 16
#define NSEG 8
#define SEG 129          // ceil(F / NSEG)
#define RING 32          // > max band width (21), power of 2
#define TPB 256
#define NTB (TT / TPB)   // 8 column-blocks
#define NBLK (BB * NTB * NSEG)  // 1024

// ---- kernel 1: extract band (start, end, 1/width) from the transform matrix.
// One wave per row; ballot-scan for first/last nonzero. Exact by construction.
__global__ __launch_bounds__(256) void band_kernel(const float* __restrict__ mtx,
                                                   int* __restrict__ bs,
                                                   int* __restrict__ be,
                                                   float* __restrict__ binv) {
    int row  = blockIdx.x * 4 + (threadIdx.x >> 6);
    int lane = threadIdx.x & 63;
    if (row >= F) return;                      // wave-uniform exit
    const float* r = mtx + (size_t)row * F;
    int first = -1, last = -1;
    for (int c = 0; c < (F + 63) / 64; ++c) {
        int j = c * 64 + lane;
        float v = (j < F) ? r[j] : 0.0f;
        unsigned long long m = __ballot(v != 0.0f);
        if (m) {
            if (first < 0) first = c * 64 + (__ffsll((unsigned long long)m) - 1);
            last = c * 64 + (63 - __clzll((long long)m));
        }
    }
    if (lane == 0) {
        bs[row]   = first;
        be[row]   = last + 1;
        binv[row] = r[first];                  // matrix stores 1/(end-start)
    }
}

// ---- kernel 2: main pass. Each thread owns one t-column and one frequency
// segment. Rows j are loaded exactly once (coalesced across lanes), diff kept
// in a 32-deep LDS ring (slot index is wave-uniform -> conflict-free).
__global__ __launch_bounds__(256) void mel_mse_kernel(const float* __restrict__ mo,
                                                      const float* __restrict__ tg,
                                                      const int* __restrict__ bs,
                                                      const int* __restrict__ be,
                                                      const float* __restrict__ binv,
                                                      double* __restrict__ partial) {
    const int tid = threadIdx.x;
    const int blk = blockIdx.x;
    const int s  = blk & (NSEG - 1);
    const int tb = (blk >> 3) & (NTB - 1);
    const int b  = blk >> 6;
    const int t  = tb * TPB + tid;

    const size_t base = (size_t)b * F * TT + (size_t)t;
    const float* __restrict__ moP = mo + base;
    const float* __restrict__ tgP = tg + base;

    __shared__ float ring[RING][TPB];          // 32 KB

    const int i0 = s * SEG;
    const int i1 = (i0 + SEG < F) ? (i0 + SEG) : F;

    const int jstart = bs[i0];                 // window warm-up start (halo)
    const int jend   = be[i1 - 1];             // last row needed

    const float C = 0.33219281f;               // log2(10)/10

    float wsum = 0.0f;
    float acc  = 0.0f;
    int   i    = i0;
    int   cs   = jstart;

    for (int j = jstart; j < jend; ++j) {
        float a = moP[(size_t)j * TT];
        float g = tgP[(size_t)j * TT];
        float d = __builtin_amdgcn_exp2f(a * C) - __builtin_amdgcn_exp2f(g * C);
        ring[j & (RING - 1)][tid] = d;
        wsum += d;
        // emit every output row whose band ends at or before j+1
        while (i < i1 && be[i] <= j + 1) {
            int si = bs[i];
            while (cs < si) {                  // shrink window from below
                wsum -= ring[cs & (RING - 1)][tid];
                ++cs;
            }
            float f = wsum * binv[i];
            acc = fmaf(f, f, acc);
            ++i;
        }
    }

    // block reduction (float within wave, double across waves)
    #pragma unroll
    for (int off = 32; off > 0; off >>= 1)
        acc += __shfl_down(acc, off, 64);

    __shared__ double wred[4];
    const int wid = tid >> 6, lane = tid & 63;
    if (lane == 0) wred[wid] = (double)acc;
    __syncthreads();
    if (tid == 0)
        partial[blk] = wred[0] + wred[1] + wred[2] + wred[3];
}

// ---- kernel 3: final reduction -> scalar mean
__global__ __launch_bounds__(256) void final_kernel(const double* __restrict__ partial,
                                                    float* __restrict__ out) {
    const int tid = threadIdx.x;
    double s = 0.0;
    for (int k = tid; k < NBLK; k += TPB) s += partial[k];
    #pragma unroll
    for (int off = 32; off > 0; off >>= 1)
        s += __shfl_down(s, off, 64);
    __shared__ double wred[4];
    const int wid = tid >> 6, lane = tid & 63;
    if (lane == 0) wred[wid] = s;
    __syncthreads();
    if (tid == 0) {
        double tot = wred[0] + wred[1] + wred[2] + wred[3];
        out[0] = (float)(tot / ((double)BB * (double)F * (double)TT));
    }
}

extern "C" void kernel_launch(void* const* d_in, const int* in_sizes, int n_in,
                              void* d_out, int out_size, void* d_ws, size_t ws_size,
                              hipStream_t stream) {
    const float* mo  = (const float*)d_in[0];
    const float* tg  = (const float*)d_in[1];
    const float* mtx = (const float*)d_in[2];

    char* ws = (char*)d_ws;
    int*    bs      = (int*)(ws);              // 1025 ints
    int*    be      = (int*)(ws + 8192);       // 1025 ints
    float*  binv    = (float*)(ws + 16384);    // 1025 floats
    double* partial = (double*)(ws + 24576);   // 1024 doubles (ends at 32 KB)

    band_kernel<<<(F + 3) / 4, TPB, 0, stream>>>(mtx, bs, be, binv);
    mel_mse_kernel<<<NBLK, TPB, 0, stream>>>(mo, tg, bs, be, binv, partial);
    final_kernel<<<1, TPB, 0, stream>>>(partial, (float*)d_out);
}

// Round 3
// 68.487 us; speedup vs baseline: 1.5847x; 1.5847x over previous
//
#include <hip/hip_runtime.h>

// MelMeanFilteredMSE: out = mean( (M @ (10^(mo/10) - 10^(tg/10)))^2 )
// M is a banded variable-width mean filter (width <= 21, band monotone).
// Sliding-window running sum along frequency; one pass over 268 MB inputs.
// R2 (resubmit after container fault): float2 loads, LDS-staged band
// schedule, 2-deep prefetch pipeline, RING=24, 768 blocks = 3/CU.

#define F 1025
#define TT 2048
#define BB 16
#define NSEG 12
#define SEG 86            // ceil(F / NSEG)
#define RING 24           // >= max live window span (<=22), proven from mel construction
#define TPB 256
#define TCH 512           // columns per block (float2 per thread)
#define NTB (TT / TCH)    // 4
#define NBLK (BB * NTB * NSEG)  // 768 = 3 blocks/CU exactly

// ---- kernel 1: extract band (start, end, 1/width) from the transform matrix.
__global__ __launch_bounds__(256) void band_kernel(const float* __restrict__ mtx,
                                                   int* __restrict__ bs,
                                                   int* __restrict__ be,
                                                   float* __restrict__ binv) {
    int row  = blockIdx.x * 4 + (threadIdx.x >> 6);
    int lane = threadIdx.x & 63;
    if (row >= F) return;                      // wave-uniform exit
    const float* r = mtx + (size_t)row * F;
    int first = -1, last = -1;
    for (int c = 0; c < (F + 63) / 64; ++c) {
        int j = c * 64 + lane;
        float v = (j < F) ? r[j] : 0.0f;
        unsigned long long m = __ballot(v != 0.0f);
        if (m) {
            if (first < 0) first = c * 64 + (__ffsll((unsigned long long)m) - 1);
            last = c * 64 + (63 - __clzll((long long)m));
        }
    }
    if (lane == 0) {
        bs[row]   = first;
        be[row]   = last + 1;
        binv[row] = r[first];                  // matrix stores 1/(end-start)
    }
}

// ---- kernel 2: main pass.
__global__ __launch_bounds__(TPB) void mel_mse_kernel(const float* __restrict__ mo,
                                                      const float* __restrict__ tg,
                                                      const int* __restrict__ bs,
                                                      const int* __restrict__ be,
                                                      const float* __restrict__ binv,
                                                      double* __restrict__ partial) {
    const int tid = threadIdx.x;
    const int blk = blockIdx.x;
    const int s  = blk % NSEG;
    const int r  = blk / NSEG;
    const int tb = r % NTB;
    const int b  = r / NTB;

    const int i0 = s * SEG;
    const int i1 = (i0 + SEG < F) ? (i0 + SEG) : F;
    const int nrows = i1 - i0;

    __shared__ float2 ring[RING * TPB];        // 48 KB
    __shared__ int    be_l[SEG];
    __shared__ int    bs_l[SEG];
    __shared__ float  binv_l[SEG];

    if (tid < nrows) {
        be_l[tid]   = be[i0 + tid];
        bs_l[tid]   = bs[i0 + tid];
        binv_l[tid] = binv[i0 + tid];
    }
    __syncthreads();

    const int jstart = bs_l[0];
    const int jend   = be_l[nrows - 1];

    const int ct = tb * TPB + tid;             // float2 column index [0, TT/2)
    const float2* __restrict__ moP = (const float2*)(mo + (size_t)b * F * TT) + ct;
    const float2* __restrict__ tgP = (const float2*)(tg + (size_t)b * F * TT) + ct;
    const size_t rs = TT / 2;                  // row stride in float2

    const float C = 0.33219281f;               // log2(10)/10

    // 2-deep software pipeline: a0/g0 = row j (ready), a1/g1 = row j+1.
    float2 a0 = moP[(size_t)jstart * rs];
    float2 g0 = tgP[(size_t)jstart * rs];
    int jp = (jstart + 1 < jend) ? (jstart + 1) : (jend - 1);
    float2 a1 = moP[(size_t)jp * rs];
    float2 g1 = tgP[(size_t)jp * rs];

    float wx = 0.0f, wy = 0.0f, acc = 0.0f;
    int j = jstart, cs = jstart, wp = 0, rp = 0;

    for (int ii = 0; ii < nrows; ++ii) {
        const int jn = be_l[ii];               // LDS broadcast, uniform
        while (j < jn) {
            const int j2 = (j + 2 < jend) ? (j + 2) : (jend - 1);
            const float2 a2 = moP[(size_t)j2 * rs];   // issue 2 rows ahead
            const float2 g2 = tgP[(size_t)j2 * rs];
            const float dx = __builtin_amdgcn_exp2f(a0.x * C) - __builtin_amdgcn_exp2f(g0.x * C);
            const float dy = __builtin_amdgcn_exp2f(a0.y * C) - __builtin_amdgcn_exp2f(g0.y * C);
            float2 dv; dv.x = dx; dv.y = dy;
            ring[wp + tid] = dv;
            wp += TPB; if (wp == RING * TPB) wp = 0;
            wx += dx; wy += dy;
            ++j;
            a0 = a1; g0 = g1; a1 = a2; g1 = g2;
        }
        const int si = bs_l[ii];
        while (cs < si) {                      // shrink window from below
            const float2 o = ring[rp + tid];
            rp += TPB; if (rp == RING * TPB) rp = 0;
            wx -= o.x; wy -= o.y;
            ++cs;
        }
        const float inv = binv_l[ii];
        const float fx = wx * inv, fy = wy * inv;
        acc = fmaf(fx, fx, fmaf(fy, fy, acc));
    }

    // block reduction (float within wave, double across waves)
    #pragma unroll
    for (int off = 32; off > 0; off >>= 1)
        acc += __shfl_down(acc, off, 64);

    __shared__ double wred[4];
    const int wid = tid >> 6, lane = tid & 63;
    if (lane == 0) wred[wid] = (double)acc;
    __syncthreads();
    if (tid == 0)
        partial[blk] = wred[0] + wred[1] + wred[2] + wred[3];
}

// ---- kernel 3: final reduction -> scalar mean
__global__ __launch_bounds__(256) void final_kernel(const double* __restrict__ partial,
                                                    float* __restrict__ out) {
    const int tid = threadIdx.x;
    double s = 0.0;
    for (int k = tid; k < NBLK; k += 256) s += partial[k];
    #pragma unroll
    for (int off = 32; off > 0; off >>= 1)
        s += __shfl_down(s, off, 64);
    __shared__ double wred[4];
    const int wid = tid >> 6, lane = tid & 63;
    if (lane == 0) wred[wid] = s;
    __syncthreads();
    if (tid == 0) {
        double tot = wred[0] + wred[1] + wred[2] + wred[3];
        out[0] = (float)(tot / ((double)BB * (double)F * (double)TT));
    }
}

extern "C" void kernel_launch(void* const* d_in, const int* in_sizes, int n_in,
                              void* d_out, int out_size, void* d_ws, size_t ws_size,
                              hipStream_t stream) {
    const float* mo  = (const float*)d_in[0];
    const float* tg  = (const float*)d_in[1];
    const float* mtx = (const float*)d_in[2];

    char* ws = (char*)d_ws;
    int*    bs      = (int*)(ws);              // 1025 ints
    int*    be      = (int*)(ws + 8192);       // 1025 ints
    float*  binv    = (float*)(ws + 16384);    // 1025 floats
    double* partial = (double*)(ws + 24576);   // 768 doubles

    band_kernel<<<(F + 3) / 4, 256, 0, stream>>>(mtx, bs, be, binv);
    mel_mse_kernel<<<NBLK, TPB, 0, stream>>>(mo, tg, bs, be, binv, partial);
    final_kernel<<<1, 256, 0, stream>>>(partial, (float*)d_out);
}